// Round 4
// baseline (144.203 us; speedup 1.0000x reference)
//
#include <hip/hip_runtime.h>

// CTC greedy decode + CTC loss, single fused kernel. B=1024, T=256, V=64.
// One block (256 thr = 4 waves) per batch row; 68KB LDS -> 2 blocks/CU.
// Phase A (all waves): coalesced load of own 16KB slice, per-row 16-lane
//   argmax+lse reduce, logits->probs in regs, probs+preds to LDS.
// Phase B/C (wave 0): label scan/scatter, prob-domain DP (8 states/lane +
//   state 512), DPP wave_shr:1 neighbor, 8-step pipelined LDS batches,
//   power-of-2 renorm (Rabiner) every 16 steps.
// out: [0,B*T) labels | [B*T,+B) lengths | [B*T+B,+B) probability

#define BB 1024
#define TT 256
#define VV 64
#define BLANKC 63
#define K_LOG2E 1.44269504088896340736f

__device__ __forceinline__ float wave_shr1(float v) {
    // v_mov_b32_dpp wave_shr:1 — lane l gets lane l-1's value; lane 0 -> 0
    return __int_as_float(__builtin_amdgcn_update_dpp(
        0, __float_as_int(v), 0x138, 0xf, 0xf, false));
}

// one DP step; Q0..Q3 = this lane's 4 label probs, PBV = blank prob
#define STEP(Q0, Q1, Q2, Q3, PBV) { \
    const float nb  = wave_shr1(a7); \
    const float na0 = (a0 + nb) * (PBV); \
    const float na1 = fmaf(sk0, nb, a1 + a0) * (Q0); \
    const float na2 = (a2 + a1) * (PBV); \
    const float na3 = fmaf(sk1, a1, a3 + a2) * (Q1); \
    const float na4 = (a4 + a3) * (PBV); \
    const float na5 = fmaf(sk2, a3, a5 + a4) * (Q2); \
    const float na6 = (a6 + a5) * (PBV); \
    const float na7 = fmaf(sk3, a5, a7 + a6) * (Q3); \
    a8 = (a8 + a7) * (PBV); \
    a0 = na0; a1 = na1; a2 = na2; a3 = na3; \
    a4 = na4; a5 = na5; a6 = na6; a7 = na7; \
}

// batched LDS reads for 8 DP steps starting at row T0 (addrspace(3) preserved)
#define LOADB(D0, D1, D2, D3, DP, T0) { \
    _Pragma("unroll") \
    for (int u = 0; u < 8; ++u) { \
        const int rbase = ((T0) + u) * 64; \
        D0[u] = P_s[rbase + vo0]; \
        D1[u] = P_s[rbase + vo1]; \
        D2[u] = P_s[rbase + vo2]; \
        D3[u] = P_s[rbase + vo3]; \
        DP[u] = P_s[rbase + BLANKC]; \
    } \
}

__global__ __launch_bounds__(256) void ctc_fused(const float* __restrict__ logits,
                                                 float* __restrict__ out)
{
    __shared__ float P_s[TT * VV];     // 64KB: per-step vocab probabilities
    __shared__ int   pred_s[TT];
    __shared__ int   lab_s[TT];
    __shared__ float alpha_s[520];

    const int tid  = threadIdx.x;
    const int lane = tid & 63;
    const int w    = tid >> 6;
    const int b    = blockIdx.x;
    const int g    = lane >> 4, li = lane & 15;

    const float4* Lg4 = (const float4*)(logits + (size_t)b * (TT * VV));

    // ---------------- Phase A: stream + per-row stats + probs ----------------
    // wave w owns row-groups r4 = w, w+4, ..., w+60 (4 rows each; 16 lanes/row)
    float4 v[16];
    #pragma unroll
    for (int i = 0; i < 16; ++i) v[i] = Lg4[(w + 4 * i) * 64 + lane];

    #pragma unroll
    for (int i = 0; i < 16; ++i) {
        const int r4 = w + 4 * i;
        const float4 x = v[i];
        float m = x.x; int idx = 0;                   // first-max semantics
        if (x.y > m) { m = x.y; idx = 1; }
        if (x.z > m) { m = x.z; idx = 2; }
        if (x.w > m) { m = x.w; idx = 3; }
        idx += li * 4;
        #pragma unroll
        for (int o = 1; o < 16; o <<= 1) {            // 16-lane group = one row
            float om = __shfl_xor(m, o, 64);
            int   oi = __shfl_xor(idx, o, 64);
            if (om > m || (om == m && oi < idx)) { m = om; idx = oi; }
        }
        float e = exp2f((x.x - m) * K_LOG2E) + exp2f((x.y - m) * K_LOG2E)
                + exp2f((x.z - m) * K_LOG2E) + exp2f((x.w - m) * K_LOG2E);
        #pragma unroll
        for (int o = 1; o < 16; o <<= 1) e += __shfl_xor(e, o, 64);
        const float lse2 = m * K_LOG2E + log2f(e);

        float4 pv;
        pv.x = exp2f(fmaf(x.x, K_LOG2E, -lse2));
        pv.y = exp2f(fmaf(x.y, K_LOG2E, -lse2));
        pv.z = exp2f(fmaf(x.z, K_LOG2E, -lse2));
        pv.w = exp2f(fmaf(x.w, K_LOG2E, -lse2));
        ((float4*)&P_s[r4 * 256])[lane] = pv;
        if (li == 15) pred_s[r4 * 4 + g] = idx;
    }
    __syncthreads();
    if (w != 0) return;                // waves 1..3 done; no barriers follow

    // ---------------- Phase B: labels (merge repeats, drop blanks) -----------
    const int4 pc = ((const int4*)pred_s)[lane];
    const int p0 = pc.x, p1 = pc.y, p2 = pc.z, p3 = pc.w;
    int pl = __shfl_up(p3, 1, 64); if (lane == 0) pl = -1;
    const int k0 = (p0 != BLANKC && p0 != pl);
    const int k1 = (p1 != BLANKC && p1 != p0);
    const int k2 = (p2 != BLANKC && p2 != p1);
    const int k3 = (p3 != BLANKC && p3 != p2);
    const int cnt = k0 + k1 + k2 + k3;
    int sc = cnt;
    #pragma unroll
    for (int off = 1; off < 64; off <<= 1) {
        int t = __shfl_up(sc, off, 64);
        if (lane >= off) sc += t;
    }
    const int length = __shfl(sc, 63, 64);
    int pos = sc - cnt;
    ((int4*)lab_s)[lane] = make_int4(BLANKC, BLANKC, BLANKC, BLANKC);
    if (k0) lab_s[pos++] = p0;         // same-wave LDS ops are program-ordered
    if (k1) lab_s[pos++] = p1;
    if (k2) lab_s[pos++] = p2;
    if (k3) lab_s[pos++] = p3;

    const int4 lq = ((const int4*)lab_s)[lane];
    ((float4*)(out + (size_t)b * TT))[lane] =
        make_float4((float)lq.x, (float)lq.y, (float)lq.z, (float)lq.w);
    if (lane == 0) out[(size_t)BB * TT + b] = (float)length;

    int lprev = __shfl_up(lq.w, 1, 64); if (lane == 0) lprev = BLANKC;
    const float sk0 = (lq.x != BLANKC && lq.x != lprev) ? 1.0f : 0.0f;
    const float sk1 = (lq.y != BLANKC && lq.y != lq.x) ? 1.0f : 0.0f;
    const float sk2 = (lq.z != BLANKC && lq.z != lq.y) ? 1.0f : 0.0f;
    const float sk3 = (lq.w != BLANKC && lq.w != lq.z) ? 1.0f : 0.0f;
    const int vo0 = lq.x, vo1 = lq.y, vo2 = lq.z, vo3 = lq.w;

    // ---------------- Phase C: forward DP (8 states/lane + state 512) --------
    float a0=0.f,a1=0.f,a2=0.f,a3=0.f,a4=0.f,a5=0.f,a6=0.f,a7=0.f,a8=0.f;
    if (lane == 0) a0 = 1.0f;
    int E = 0;

    float qA0[8], qA1[8], qA2[8], qA3[8], pA[8];
    float qB0[8], qB1[8], qB2[8], qB3[8], pB[8];

    LOADB(qA0, qA1, qA2, qA3, pA, 0);
    #pragma unroll 1
    for (int c = 0; c < 16; ++c) {                    // 16 steps per iter
        const int t0 = c * 16;
        LOADB(qB0, qB1, qB2, qB3, pB, t0 + 8);
        #pragma unroll
        for (int u = 0; u < 8; ++u) STEP(qA0[u], qA1[u], qA2[u], qA3[u], pA[u]);
        if (c < 15) LOADB(qA0, qA1, qA2, qA3, pA, t0 + 16);
        #pragma unroll
        for (int u = 0; u < 8; ++u) STEP(qB0[u], qB1[u], qB2[u], qB3[u], pB[u]);

        // renorm every 16 steps: exact power-of-2 scaling, exponent into E
        float M = fmaxf(fmaxf(fmaxf(a0, a1), fmaxf(a2, a3)),
                        fmaxf(fmaxf(a4, a5), fmaxf(a6, a7)));
        M = fmaxf(M, a8);
        #pragma unroll
        for (int o = 1; o < 64; o <<= 1)
            M = fmaxf(M, __shfl_xor(M, o, 64));
        int e = (int)((__float_as_uint(M) >> 23) & 255) - 127;
        if (M == 0.0f) e = 0;
        E += e;
        const float scl = __int_as_float((127 - e) << 23);    // 2^-e
        a0*=scl; a1*=scl; a2*=scl; a3*=scl; a4*=scl;
        a5*=scl; a6*=scl; a7*=scl; a8*=scl;
    }

    // ---------------- epilogue: probability ----------------------------------
    ((float4*)alpha_s)[2 * lane]     = make_float4(a0, a1, a2, a3);
    ((float4*)alpha_s)[2 * lane + 1] = make_float4(a4, a5, a6, a7);
    if (lane == 63) alpha_s[512] = a8;
    if (lane == 0) {
        const int end = 2 * length;
        const float e1 = alpha_s[end];
        const float e2 = (length > 0) ? alpha_s[end - 1] : 0.0f;
        out[(size_t)BB * TT + BB + b] = exp2f(log2f(e1 + e2) + (float)E);
    }
}

extern "C" void kernel_launch(void* const* d_in, const int* in_sizes, int n_in,
                              void* d_out, int out_size, void* d_ws, size_t ws_size,
                              hipStream_t stream)
{
    const float* logits = (const float*)d_in[0];
    float* out = (float*)d_out;
    hipLaunchKernelGGL(ctc_fused, dim3(BB), dim3(256), 0, stream, logits, out);
}